// Round 2
// baseline (329.741 us; speedup 1.0000x reference)
//
#include <hip/hip_runtime.h>
#include <hip/hip_bf16.h>

// ---------------------------------------------------------------------------
// GHN (float32 I/O): encode (3 gathered GEMMs, bf16 MFMA, f32 acc)
//   -> 2-layer GCN (pure f32 vector) -> decode (gathered GEMMs, MFMA) -> f32
// Inputs/outputs are float32; bf16 used only as MFMA operand format.
// ---------------------------------------------------------------------------

typedef __attribute__((ext_vector_type(8))) __bf16 bf16x8;
typedef __attribute__((ext_vector_type(4))) float f32x4;

#define MFMA16(a,b,c) __builtin_amdgcn_mfma_f32_16x16x32_bf16((a),(b),(c),0,0,0)

__device__ __forceinline__ bf16x8 cvt8(const float* p) {
    float4 a = *(const float4*)p;
    float4 b = *(const float4*)(p + 4);
    bf16x8 r;
    r[0]=(__bf16)a.x; r[1]=(__bf16)a.y; r[2]=(__bf16)a.z; r[3]=(__bf16)a.w;
    r[4]=(__bf16)b.x; r[5]=(__bf16)b.y; r[6]=(__bf16)b.z; r[7]=(__bf16)b.w;
    return r;
}

// ---------------------------------------------------------------------------
// k_enc: enc[n][h] = sum_k A[n][k] * EncW[h][col(k)] via mfma_16x16x32_bf16.
// MFMA layouts (m89/m91-verified): A[m=lane&15][k=(lane>>4)*8+j],
// B[k=(lane>>4)*8+j][n=lane&15], D col=lane&15, row=(lane>>4)*4+reg.
// K split across blocks (ks) and waves (w); waves reduced in LDS ->
// P[slot=ks][node][32]. Trailing blocks compute dinv.
// ---------------------------------------------------------------------------
template<int KSTEPS, int DIV>
__device__ __forceinline__ void enc_tile(const float* Ar,
                                         const float* B0,
                                         const float* B1,
                                         int kw, int kg, f32x4& acc0, f32x4& acc1)
{
#pragma unroll
    for (int s = 0; s < KSTEPS; ++s) {
        int k = kw + s*32 + kg*8;
        int col = DIV ? (k + (k/DIV)*DIV) : k;   // gathered (padded) column
        bf16x8 a  = cvt8(Ar + k);
        bf16x8 b0 = cvt8(B0 + col);
        bf16x8 b1 = cvt8(B1 + col);
        acc0 = MFMA16(a, b0, acc0);
        acc1 = MFMA16(a, b1, acc1);
    }
}

__global__ __launch_bounds__(256) void k_enc(
    const float* __restrict__ conv_w,
    const float* __restrict__ lin_w,
    const float* __restrict__ bias_w,
    const float* __restrict__ conv_enc_w,
    const float* __restrict__ lin_enc_w,
    const float* __restrict__ bias_enc_w,
    const int* __restrict__ adj,
    float* __restrict__ P, float* __restrict__ dinv)
{
    int b = blockIdx.x, tid = threadIdx.x;
    int w = tid >> 6, lane = tid & 63;
    int n16 = lane & 15, kg = lane >> 4;

    if (b >= 592) {  // ---- dinv rows: dinv[i] = 1/sqrt(1 + sum_j adj[i][j])
        int wid = (b - 592)*4 + w;
        for (int r = wid; r < 1025; r += 256) {
            const int* row = adj + (size_t)r*1025;
            int s = 0;
#pragma unroll
            for (int i = 0; i <= 16; ++i) {
                int j = lane + i*64;
                if (j < 1025) s += row[j];
            }
#pragma unroll
            for (int off = 32; off; off >>= 1) s += __shfl_xor(s, off, 64);
            if (lane == 0) dinv[r] = 1.0f / sqrtf((float)s + 1.0f);
        }
        return;
    }

    f32x4 acc0 = {0.f,0.f,0.f,0.f}, acc1 = {0.f,0.f,0.f,0.f};
    int slot, nodebase, mtile;
    if (b < 512) {            // conv encoder: M=512, K=36864, 16 ks x 4 waves
        mtile = b >> 4; int ks = b & 15;
        slot = ks; nodebase = 0;
        const float* Ar = conv_w     + (size_t)(mtile*16 + n16)*36864;
        const float* B0 = conv_enc_w + (size_t)n16*147456;
        const float* B1 = conv_enc_w + (size_t)(16+n16)*147456;
        enc_tile<18,576>(Ar, B0, B1, ks*2304 + w*576, kg, acc0, acc1);
    } else if (b < 576) {     // lin encoder: M=256, K=4096, 4 ks x 4 waves
        int bb = b - 512; mtile = bb >> 2; int ks = bb & 3;
        slot = ks; nodebase = 512;
        const float* Ar = lin_w     + (size_t)(mtile*16 + n16)*4096;
        const float* B0 = lin_enc_w + (size_t)n16*16384;
        const float* B1 = lin_enc_w + (size_t)(16+n16)*16384;
        enc_tile<8,64>(Ar, B0, B1, ks*1024 + w*256, kg, acc0, acc1);
    } else {                  // bias encoder: M=256, K=64 (waves 2,3 idle)
        mtile = b - 576; slot = 0; nodebase = 768;
        if (w < 2) {
            const float* Ar = bias_w     + (size_t)(mtile*16 + n16)*64;
            const float* B0 = bias_enc_w + (size_t)n16*128;
            const float* B1 = bias_enc_w + (size_t)(16+n16)*128;
            enc_tile<1,0>(Ar, B0, B1, w*32, kg, acc0, acc1);
        }
    }

    // in-block reduction of the 4 waves' 16x32 tiles
    __shared__ float R[4*16*32];
#pragma unroll
    for (int r = 0; r < 4; ++r) {
        R[(w*16 + kg*4 + r)*32 + n16]      = acc0[r];
        R[(w*16 + kg*4 + r)*32 + 16 + n16] = acc1[r];
    }
    __syncthreads();
    for (int e = tid; e < 512; e += 256) {
        float s = R[e] + R[512+e] + R[1024+e] + R[1536+e];
        int nl = e >> 5, h = e & 31;
        int node = nodebase + mtile*16 + nl;
        P[((size_t)slot*1024 + node)*32 + h] = s;
    }
}

// ---------------------------------------------------------------------------
// k_z1: reduce encoder partials (+bias), build emb; Z1s[i] = dinv[i] *
//       ( e[i] @ (W1[0:32]+W1[32:64]) + m[i] @ W1[64:96] ).  Row 0: e=m=1.
// ---------------------------------------------------------------------------
__global__ __launch_bounds__(256) void k_z1(
    const float* __restrict__ P,
    const float* __restrict__ conv_enc_b,
    const float* __restrict__ lin_enc_b,
    const float* __restrict__ bias_enc_b,
    const float* __restrict__ embed_tab,
    const int* __restrict__ prims,
    const float* __restrict__ gcn_w1,
    const float* __restrict__ dinv,
    float* __restrict__ Z1s)
{
    __shared__ float El[8*32], Ml[8*32];
    int tid = threadIdx.x;
    int i0 = blockIdx.x * 8;
    {
        int rl = tid >> 5, h = tid & 31;
        int i = i0 + rl;
        if (i < 1025) {
            float e, m;
            if (i == 0) { e = 1.0f; m = 1.0f; }
            else {
                int node = i - 1;
                int ns; float bias;
                if (node < 512)      { ns = 16; bias = conv_enc_b[h]; }
                else if (node < 768) { ns = 4;  bias = lin_enc_b[h];  }
                else                 { ns = 1;  bias = bias_enc_b[h]; }
                float s = bias;
                for (int sl = 0; sl < ns; ++sl)
                    s += P[((size_t)sl*1024 + node)*32 + h];
                e = s;
                m = embed_tab[prims[node]*32 + h];
            }
            El[rl*32+h] = e; Ml[rl*32+h] = m;
        }
    }
    __syncthreads();
    if (tid < 192) {
        int rl = tid / 24, c4 = tid % 24;
        int i = i0 + rl;
        if (i < 1025) {
            float a0=0,a1=0,a2=0,a3=0;
            for (int h = 0; h < 32; ++h) {
                float e = El[rl*32+h], m = Ml[rl*32+h];
                float4 wa = *(const float4*)(gcn_w1 + h*96 + c4*4);
                float4 wb = *(const float4*)(gcn_w1 + (h+32)*96 + c4*4);
                float4 wc = *(const float4*)(gcn_w1 + (h+64)*96 + c4*4);
                a0 += e*(wa.x+wb.x) + m*wc.x;
                a1 += e*(wa.y+wb.y) + m*wc.y;
                a2 += e*(wa.z+wb.z) + m*wc.z;
                a3 += e*(wa.w+wb.w) + m*wc.w;
            }
            float di = dinv[i];
            float* o = Z1s + (size_t)i*96 + c4*4;
            o[0] = di*a0; o[1] = di*a1; o[2] = di*a2; o[3] = di*a3;
        }
    }
}

// ---------------------------------------------------------------------------
// k_prop: red[i] = sum_j (adj[i][j]+I) * Zs[j]  (Zs pre-scaled by dinv[j]).
// mode 0: Zout[i] = dinv[i] * ( relu(dinv[i]*red[i]) @ W2 )
// mode 1: Xb[i]  = bf16( dinv[i]*red[i] )     (decoder A operand, internal)
// ---------------------------------------------------------------------------
__global__ __launch_bounds__(256) void k_prop(
    const float* __restrict__ Zs, const int* __restrict__ adj,
    const float* __restrict__ dinv, const float* __restrict__ gcn_w2,
    float* __restrict__ Zout, unsigned short* __restrict__ Xb, int mode)
{
    __shared__ float adjf[4*1025];
    __shared__ float red[4*96];
    int tid = threadIdx.x;
    int i0 = blockIdx.x * 4;
    int nr = (1025 - i0 < 4) ? (1025 - i0) : 4;
    for (int idx = tid; idx < nr*1025; idx += 256)
        adjf[idx] = (float)adj[(size_t)i0*1025 + idx];
    for (int idx = nr*1025 + tid; idx < 4*1025; idx += 256)
        adjf[idx] = 0.f;                                 // last-block tail
    red[tid] = 0.f; if (tid < 128) red[256+tid] = 0.f;
    __syncthreads();
    if (tid < nr) adjf[tid*1025 + i0 + tid] += 1.0f;     // + identity
    __syncthreads();

    if (tid < 240) {
        int c4 = tid % 24, jg = tid / 24;
        float acc[4][4] = {};
        for (int j = jg; j < 1025; j += 10) {
            const float4 z = *(const float4*)(Zs + (size_t)j*96 + c4*4);
#pragma unroll
            for (int r = 0; r < 4; ++r) {
                float av = adjf[r*1025 + j];
                acc[r][0] += av*z.x; acc[r][1] += av*z.y;
                acc[r][2] += av*z.z; acc[r][3] += av*z.w;
            }
        }
#pragma unroll
        for (int r = 0; r < 4; ++r) {
            atomicAdd(&red[r*96 + c4*4 + 0], acc[r][0]);
            atomicAdd(&red[r*96 + c4*4 + 1], acc[r][1]);
            atomicAdd(&red[r*96 + c4*4 + 2], acc[r][2]);
            atomicAdd(&red[r*96 + c4*4 + 3], acc[r][3]);
        }
    }
    __syncthreads();

    if (mode == 0) {
        if (tid < 96) {
            int rl = tid / 24, c4 = tid % 24;
            int i = i0 + rl;
            if (rl < nr) {
                float di = dinv[i];
                float o0=0,o1=0,o2=0,o3=0;
                for (int c = 0; c < 96; ++c) {
                    float hv = red[rl*96+c]*di; hv = hv > 0.f ? hv : 0.f;
                    float4 w2 = *(const float4*)(gcn_w2 + c*96 + c4*4);
                    o0 += hv*w2.x; o1 += hv*w2.y; o2 += hv*w2.z; o3 += hv*w2.w;
                }
                float* o = Zout + (size_t)i*96 + c4*4;
                o[0] = di*o0; o[1] = di*o1; o[2] = di*o2; o[3] = di*o3;
            }
        }
    } else {
        for (int idx = tid; idx < nr*96; idx += 256) {
            int rl = idx / 96, c = idx % 96;
            int i = i0 + rl;
            __hip_bfloat16 hb = __float2bfloat16(dinv[i]*red[rl*96+c]);
            Xb[(size_t)i*96 + c] = *(unsigned short*)&hb;
        }
    }
}

// ---------------------------------------------------------------------------
// k_dec: out[n][kc] = Xb_row(n) . DecW[row(kc)] + DecB[row(kc)], MFMA over
// K=96 (3 steps), only valid (sliced) columns computed. f32 output.
// ---------------------------------------------------------------------------
__global__ __launch_bounds__(256) void k_dec(
    const unsigned short* __restrict__ Xb,
    const float* __restrict__ cW, const float* __restrict__ cB,
    const float* __restrict__ lW, const float* __restrict__ lB,
    const float* __restrict__ bW, const float* __restrict__ bB,
    float* __restrict__ out)
{
    int b = blockIdx.x, tid = threadIdx.x;
    int w = tid >> 6, lane = tid & 63;
    int n16 = lane & 15, kg = lane >> 4;

    const float *W, *Bv;
    int g0, kcw, ncols, div, ostride;
    size_t obase;
    if (b < 576) {                       // conv decoder
        int kb = b >> 1, mb = b & 1;
        W = cW; Bv = cB; g0 = 1 + mb*256; kcw = kb*128 + w*32; ncols = 36864;
        div = 576; obase = (size_t)mb*256*36864; ostride = 36864;
    } else if (b < 608) {                // lin decoder
        int kb = b - 576;
        W = lW; Bv = lB; g0 = 513; kcw = kb*128 + w*32; ncols = 4096;
        div = 64; obase = (size_t)18874368; ostride = 4096;
    } else {                             // bias decoder
        W = bW; Bv = bB; g0 = 769; kcw = w*32; ncols = 64;
        div = 0; obase = (size_t)19922944; ostride = 64;
    }
    if (kcw >= ncols) return;

    int kc_a = kcw + n16, kc_b = kcw + 16 + n16;
    int row_a = div ? kc_a + (kc_a/div)*div : kc_a;   // padded row index
    int row_b = div ? kc_b + (kc_b/div)*div : kc_b;
    const float* Wa = W + (size_t)row_a*96 + kg*8;
    const float* Wb = W + (size_t)row_b*96 + kg*8;
    bf16x8 ba0 = cvt8(Wa);
    bf16x8 ba1 = cvt8(Wa + 32);
    bf16x8 ba2 = cvt8(Wa + 64);
    bf16x8 bb0 = cvt8(Wb);
    bf16x8 bb1 = cvt8(Wb + 32);
    bf16x8 bb2 = cvt8(Wb + 64);
    float bva = Bv[row_a], bvb = Bv[row_b];

#pragma unroll 2
    for (int mt = 0; mt < 16; ++mt) {
        const unsigned short* Ar = Xb + (size_t)(g0 + mt*16 + n16)*96 + kg*8;
        bf16x8 a0 = *(const bf16x8*)(Ar);
        bf16x8 a1 = *(const bf16x8*)(Ar + 32);
        bf16x8 a2 = *(const bf16x8*)(Ar + 64);
        f32x4 acc0 = {0.f,0.f,0.f,0.f}, acc1 = {0.f,0.f,0.f,0.f};
        acc0 = MFMA16(a0, ba0, acc0);
        acc0 = MFMA16(a1, ba1, acc0);
        acc0 = MFMA16(a2, ba2, acc0);
        acc1 = MFMA16(a0, bb0, acc1);
        acc1 = MFMA16(a1, bb1, acc1);
        acc1 = MFMA16(a2, bb2, acc1);
#pragma unroll
        for (int r = 0; r < 4; ++r) {
            int node = mt*16 + kg*4 + r;
            out[obase + (size_t)node*ostride + kc_a] = acc0[r] + bva;
            out[obase + (size_t)node*ostride + kc_b] = acc1[r] + bvb;
        }
    }
}

// ---------------------------------------------------------------------------
extern "C" void kernel_launch(void* const* d_in, const int* in_sizes, int n_in,
                              void* d_out, int out_size, void* d_ws, size_t ws_size,
                              hipStream_t stream)
{
    const float* conv_w     = (const float*)d_in[0];
    const float* lin_w      = (const float*)d_in[1];
    const float* bias_w     = (const float*)d_in[2];
    const float* conv_enc_w = (const float*)d_in[3];
    const float* conv_enc_b = (const float*)d_in[4];
    const float* lin_enc_w  = (const float*)d_in[5];
    const float* lin_enc_b  = (const float*)d_in[6];
    const float* bias_enc_w = (const float*)d_in[7];
    const float* bias_enc_b = (const float*)d_in[8];
    const float* gcn_w1     = (const float*)d_in[9];
    const float* gcn_w2     = (const float*)d_in[10];
    const float* conv_dec_w = (const float*)d_in[11];
    const float* conv_dec_b = (const float*)d_in[12];
    const float* lin_dec_w  = (const float*)d_in[13];
    const float* lin_dec_b  = (const float*)d_in[14];
    const float* bias_dec_w = (const float*)d_in[15];
    const float* bias_dec_b = (const float*)d_in[16];
    const float* embed_tab  = (const float*)d_in[17];
    const int*   adj        = (const int*)d_in[18];
    const int*   prims      = (const int*)d_in[19];

    // workspace layout (floats): P 16*1024*32 | Z1s | Z2s | dinv | Xb(bf16)
    float* P    = (float*)d_ws;             // 524288 f = 2 MB
    float* Z1s  = P + (size_t)16*1024*32;   // 98400 f
    float* Z2s  = Z1s + 1025*96;            // 98400 f
    float* dinv = Z2s + 1025*96;            // 1056 f
    unsigned short* Xb = (unsigned short*)(dinv + 1056);  // 1025*96 bf16

    k_enc<<<656, 256, 0, stream>>>(conv_w, lin_w, bias_w,
                                   conv_enc_w, lin_enc_w, bias_enc_w,
                                   adj, P, dinv);
    k_z1<<<129, 256, 0, stream>>>(P, conv_enc_b, lin_enc_b, bias_enc_b,
                                  embed_tab, prims, gcn_w1, dinv, Z1s);
    k_prop<<<257, 256, 0, stream>>>(Z1s, adj, dinv, gcn_w2, Z2s, Xb, 0);
    k_prop<<<257, 256, 0, stream>>>(Z2s, adj, dinv, gcn_w2, Z2s, Xb, 1);
    k_dec<<<609, 256, 0, stream>>>(Xb, conv_dec_w, conv_dec_b,
                                   lin_dec_w, lin_dec_b,
                                   bias_dec_w, bias_dec_b,
                                   (float*)d_out);
}